// Round 2
// baseline (27078.879 us; speedup 1.0000x reference)
//
#include <hip/hip_runtime.h>
#include <cstdint>
#include <cstddef>

// ---------------------------------------------------------------------------
// Tacotron decoder, MI355X. Round 4: pair-split — 2 CUs per batch row.
// R1 post-mortem: phase-merge gained only 3.5% -> time is in-phase streaming
// (per-CU L2 port ~144 GB/s x 3.3MB weights/step = ~30us floor) + VALU,
// with half the chip idle. Fix: 256 blocks x 512 thr, blocks (2b, 2b+1)
// cooperate on row b. GEMVs split by N-half (or K-split over freshly-owned
// state slices); attention split by t-half. 10 pairwise exchanges/step via
// relaxed agent-scope atomics (sc1 bypass, no wbl2 fences) + spin flags.
// Co-residency guaranteed: <=54KB LDS, <=128 VGPR -> 2 blocks/CU capacity.
// ---------------------------------------------------------------------------

#define TDEC   250
#define BATCH  128

#define ALPHA_OFF  ((size_t)12800000)        // 128*1250*80 floats
#define WP_OFF     ((size_t)45568000)

// ---- ws byte offsets ----
#define WS_WACC_B   ((size_t)0)
#define WS_FLAG_B   ((size_t)1024)
#define WS_COMM_B   ((size_t)4096)
#define COMM_STRIDE 4096                     // floats per (row,half)
#define WS_WGT_B    (WS_COMM_B + (size_t)256 * COMM_STRIDE * 4)   // 4,198,400
#define WGT_ELEMS   1658880
#define WS_KEYS_B   (WS_WGT_B + (size_t)WGT_ELEMS * 2)
#define WS_ENC_B    (WS_KEYS_B + (size_t)33554432 * 2)

// ---- comm event offsets (floats) ----
#define CO_E0 0        // p1 half      (128)
#define CO_E1 128      // p half       (64)
#define CO_E2 192      // att g half(256)@192, cx half(128)@448
#define CO_E3 576      // h_att slice(128)@576, q partial(256)@704
#define CO_E4 960      // softmax denom partial (1)
#define CO_E5 1024     // ctx partial  (256)
#define CO_E6 1280     // dec_in half  (128)
#define CO_E7 1408     // dec1 g half(256)@1408, cx half(128)@1664
#define CO_E8 1792     // h1 slice(128)@1792, g2 part(512)@1920, cx2 part(256)@2432
#define CO_E9 2688     // h2 slice(128)@2688, dense part(512)@2816

// ---- weight offsets (bf16 elems) ----
#define OFF_PRE_W1   0          // 80x256
#define OFF_PRE_W2   20480      // 256x128
#define OFF_ATT_WG   53248      // 640x512
#define OFF_ATT_WC   380928     // 640x256 (rows 0..383 = x-part)
#define OFF_ATT_WCH  479232     // rows 384..639 (r*h part)
#define OFF_ATTN_WQ  544768     // 256x256
#define OFF_DECI_W   610304     // 512x256
#define OFF_DEC1_WG  741376     // 512x512
#define OFF_DEC1_WC  1003520    // 512x256 (rows 0..255 = x-part)
#define OFF_DEC1_WCH 1069056    // rows 256..511
#define OFF_DEC2_WG  1134592    // 512x512  (ROW-REORDERED: [0:128,256:384,128:256,384:512])
#define OFF_DEC2_WC  1396736    // 512x256
#define OFF_DEC2_WCH 1462272    // rows 256..511
#define OFF_OUT_WP   1527808    // 256x512 (padded from 256x400)

__device__ inline unsigned short f2bf(float f){
    unsigned int u = __float_as_uint(f);
    u = (u + 0x7fffu + ((u >> 16) & 1u)) >> 16;
    return (unsigned short)u;
}
__device__ inline float ftanh(float x){
    float e = __expf(2.f * x);
    return 1.f - 2.f * __builtin_amdgcn_rcpf(e + 1.f);
}
__device__ inline float fsig(float x){
    return __builtin_amdgcn_rcpf(1.f + __expf(-x));
}

// ---- cross-block comm primitives (relaxed agent atomics = sc1 bypass) -----
__device__ inline void cput(float* cm, int i, float v){
    __hip_atomic_store(cm + i, v, __ATOMIC_RELAXED, __HIP_MEMORY_SCOPE_AGENT);
}
__device__ inline float cget(const float* cm, int i){
    return __hip_atomic_load(cm + i, __ATOMIC_RELAXED, __HIP_MEMORY_SCOPE_AGENT);
}
// Precondition: comm stores for this event already issued by all threads.
// First __syncthreads drains vmcnt(0) (hipcc emits full waitcnt before
// s_barrier), so data is at fabric before the flag store.
__device__ inline void pair_wait(int* flags, int fm, int fo, int T, int tid){
    __syncthreads();
    if (tid == 0){
        __hip_atomic_store(&flags[fm], T, __ATOMIC_RELAXED, __HIP_MEMORY_SCOPE_AGENT);
        asm volatile("" ::: "memory");
        while (__hip_atomic_load(&flags[fo], __ATOMIC_RELAXED, __HIP_MEMORY_SCOPE_AGENT) < T)
            __builtin_amdgcn_s_sleep(1);
    }
    __syncthreads();
}

// ---------------- bf16 half-GEMV partials (512-thread blocks) ---------------
// scratch[part][NW] = x[part-slice] @ W; W pre-offset to (row0, col0);
// row stride = NFULL elems.
template<int K, int NFULL, int NW, int PARTS>
__device__ inline void gemv_h(const unsigned short* __restrict__ W,
                              const float* __restrict__ x,
                              float* __restrict__ scratch, int tid)
{
    constexpr int CH = NW / 8;
    constexpr int LG = (CH == 8) ? 3 : (CH == 16) ? 4 : (CH == 32) ? 5 : 6;
    constexpr int KCNT = K / PARTS;
    static_assert(KCNT * PARTS == K, "K must divide");
    static_assert(CH * PARTS <= 512, "too many threads");
    const int chunk = tid & (CH - 1);
    const int part  = tid >> LG;
    if (PARTS == (512 >> LG) || part < PARTS){
        const uint4* Wp = (const uint4*)W + (size_t)(part * KCNT) * (NFULL / 8) + chunk;
        const float* xp = x + part * KCNT;
        float a0=0.f,a1=0.f,a2=0.f,a3=0.f,a4=0.f,a5=0.f,a6=0.f,a7=0.f;
        #pragma unroll 8
        for (int k = 0; k < KCNT; k++){
            uint4 w = Wp[(size_t)k * (NFULL / 8)];
            float xv = xp[k];
            a0 = fmaf(__uint_as_float(w.x << 16),         xv, a0);
            a1 = fmaf(__uint_as_float(w.x & 0xffff0000u), xv, a1);
            a2 = fmaf(__uint_as_float(w.y << 16),         xv, a2);
            a3 = fmaf(__uint_as_float(w.y & 0xffff0000u), xv, a3);
            a4 = fmaf(__uint_as_float(w.z << 16),         xv, a4);
            a5 = fmaf(__uint_as_float(w.z & 0xffff0000u), xv, a5);
            a6 = fmaf(__uint_as_float(w.w << 16),         xv, a6);
            a7 = fmaf(__uint_as_float(w.w & 0xffff0000u), xv, a7);
        }
        float4* s4 = (float4*)(scratch + part * NW + chunk * 8);
        s4[0] = float4{a0, a1, a2, a3};
        s4[1] = float4{a4, a5, a6, a7};
    }
}

template<int NW, int PARTS>
__device__ inline float red_parts(const float* __restrict__ scratch, int n){
    float s = 0.f;
    #pragma unroll
    for (int p = 0; p < PARTS; p++) s += scratch[p * NW + n];
    return s;
}

// ---------------- prep: fp32 -> bf16 conversions ----------------------------
__global__ void k_cvt_flat(const float* __restrict__ src, unsigned short* __restrict__ dst, int n){
    int i = blockIdx.x * 256 + threadIdx.x;
    if (i < n) dst[i] = f2bf(src[i]);
}
__global__ void k_cvt_pad(const float* __restrict__ src, unsigned short* __restrict__ dst){
    int i = blockIdx.x * 256 + threadIdx.x;   // i < 256*512
    int k = i >> 9, n = i & 511;
    dst[i] = (n < 400) ? f2bf(src[k * 400 + n]) : (unsigned short)0;
}
// dec2_Wg row reorder: orig chunks [c0,c1,c2,c3] (128 rows each) -> [c0,c2,c1,c3]
// so block h's K-split rows {o1-half, h2-half} are contiguous at h*256.
__global__ void k_cvt_wg2(const float* __restrict__ src, unsigned short* __restrict__ dst){
    int i = blockIdx.x * 256 + threadIdx.x;   // i < 512*512
    int r = i >> 9, n = i & 511;
    int c = r >> 7;
    int nc = (c == 1) ? 2 : (c == 2) ? 1 : c;
    int nr = nc * 128 + (r & 127);
    dst[nr * 512 + n] = f2bf(src[i]);
}

// ---------------- K1: keys_T[b][d][t] = bf16(enc @ Wk + bk) -----------------
__global__ __launch_bounds__(256) void k_keys(const float* __restrict__ enc,
                                              const float* __restrict__ Wk,
                                              const float* __restrict__ bk,
                                              unsigned short* __restrict__ keysT)
{
    __shared__ __align__(16) float Wt[64 * 256];   // [kk][d]
    __shared__ float At[64 * 64];                  // [r][kk]
    __shared__ unsigned short tileT[256 * 68];     // [d][t_loc], pad 68
    const int tid = threadIdx.x;
    const size_t row0 = (size_t)blockIdx.x * 64;
    const int dq = tid & 63;
    const int rg = tid >> 6;

    float4 acc[16];
    #pragma unroll
    for (int i = 0; i < 16; i++) acc[i] = float4{0.f, 0.f, 0.f, 0.f};

    for (int k0 = 0; k0 < 256; k0 += 64){
        __syncthreads();
        #pragma unroll
        for (int i = 0; i < 64; i++)
            Wt[i * 256 + tid] = Wk[(size_t)(k0 + i) * 256 + tid];
        #pragma unroll
        for (int i = 0; i < 16; i++){
            int idx = tid + i * 256;
            int r = idx >> 6, kk = idx & 63;
            At[idx] = enc[(row0 + r) * 256 + k0 + kk];
        }
        __syncthreads();
        for (int kk = 0; kk < 64; kk++){
            float4 w = ((const float4*)Wt)[kk * 64 + dq];
            #pragma unroll
            for (int rr = 0; rr < 16; rr++){
                float a = At[(rg * 16 + rr) * 64 + kk];
                acc[rr].x += a * w.x; acc[rr].y += a * w.y;
                acc[rr].z += a * w.z; acc[rr].w += a * w.w;
            }
        }
    }
    float4 bb = ((const float4*)bk)[dq];
    __syncthreads();
    #pragma unroll
    for (int rr = 0; rr < 16; rr++){
        int t_loc = rg * 16 + rr;
        #pragma unroll
        for (int c = 0; c < 4; c++){
            float val = (&acc[rr].x)[c] + (&bb.x)[c];
            int d = dq * 4 + c;
            tileT[d * 68 + t_loc] = f2bf(val);
        }
    }
    __syncthreads();
    const int b_ = (int)(row0 >> 10);
    const int t0 = (int)(row0 & 1023);
    #pragma unroll
    for (int i = 0; i < 16; i++){
        int flat = tid + i * 256;
        int d = flat >> 4, tq = flat & 15;
        ushort4 v = *(const ushort4*)&tileT[d * 68 + tq * 4];
        *(ushort4*)&keysT[(((size_t)(b_ * 256 + d)) << 10) + t0 + tq * 4] = v;
    }
}

// ---------------- K2: main recurrent kernel, 2 blocks per batch row ---------
struct KParams {
    const int *imask; const float *inp_att; const float *style_tok;
    const float *pre_b1, *pre_b2, *att_bg, *att_bc, *attn_bq, *attn_v;
    const float *deci_b, *dec1_bg, *dec1_bc, *dec2_bg, *dec2_bc, *out_b;
    const unsigned short *wgt;
    const unsigned short *keysT;    // [128][256][1024] bf16
    const unsigned short *encb;     // [128][1024][256] bf16
    float *wacc; float *comm; int *flags; float *out;
};

__global__ __launch_bounds__(512, 4) void k_main(KParams p)
{
    __shared__ __align__(16) float scr [4096];
    __shared__ __align__(16) float scr2[4096];
    __shared__ float xa[640];        // [ctx 0:256 | p 256:384 | h_att 384:640]
    __shared__ float xbuf[512];      // xr / xd / xg1 / xg2loc (phase-local)
    __shared__ float g_l[512], cx_l[256];
    __shared__ float h1[256], h2[256], dci[256], o1_l[256], o2loc[128];
    __shared__ float p1_l[256];
    __shared__ float stylel[256], astylel[256], v_l[256], q_l[256];
    __shared__ float e_l[512];
    __shared__ float last_o[80];
    __shared__ float red[16];

    const int tid = threadIdx.x;
    const int b   = blockIdx.x >> 1;      // batch row
    const int h   = blockIdx.x & 1;       // half index
    const int mlen = p.imask[b];
    const unsigned short* W = p.wgt;

    float* cm = p.comm + (size_t)(2 * b + h) * COMM_STRIDE;        // mine
    const float* co = p.comm + (size_t)(2 * b + (1 - h)) * COMM_STRIDE; // other's
    const int fm = 2 * b + h, fo = 2 * b + (1 - h);
    int seq = 0;

    if (tid < 256){
        xa[384 + tid] = 0.f;   // h_att
        xa[tid] = 0.f;         // ctx
        h1[tid] = 0.f; h2[tid] = 0.f;
        float s = 0.f;
        #pragma unroll
        for (int k = 0; k < 10; k++) s += p.inp_att[b * 10 + k] * p.style_tok[k * 256 + tid];
        stylel[tid] = s; astylel[tid] = fabsf(s);
        v_l[tid] = p.attn_v[tid];
    }
    if (tid < 80) last_o[tid] = 0.f;
    __syncthreads();

    for (int s = 0; s < TDEC; s++){
        // ---- P1: prenet1 (80->256 relu), N-split ----
        gemv_h<80, 256, 128, 16>(W + OFF_PRE_W1 + h * 128, last_o, scr, tid);
        __syncthreads();
        if (tid < 128){
            float v = fmaxf(p.pre_b1[h * 128 + tid] + red_parts<128,16>(scr, tid), 0.f);
            p1_l[h * 128 + tid] = v;
            cput(cm, CO_E0 + tid, v);
        }
        pair_wait(p.flags, fm, fo, ++seq, tid);
        if (tid < 128) p1_l[(1 - h) * 128 + tid] = cget(co, CO_E0 + tid);
        __syncthreads();

        // ---- P2: prenet2 (256->128 relu), N-split ----
        gemv_h<256, 128, 64, 64>(W + OFF_PRE_W2 + h * 64, p1_l, scr, tid);
        __syncthreads();
        if (tid < 64){
            float v = fmaxf(p.pre_b2[h * 64 + tid] + red_parts<64,64>(scr, tid), 0.f);
            xa[256 + h * 64 + tid] = v;
            cput(cm, CO_E1 + tid, v);
        }
        pair_wait(p.flags, fm, fo, ++seq, tid);
        if (tid < 64) xa[256 + (1 - h) * 64 + tid] = cget(co, CO_E1 + tid);
        __syncthreads();

        // ---- P3: att GRU A: g=sig(xa@Wg), cx = bc + xa[0:384]@Wc_x, N-split
        gemv_h<640, 512, 256, 16>(W + OFF_ATT_WG + h * 256, xa, scr,  tid);
        gemv_h<384, 256, 128, 32>(W + OFF_ATT_WC + h * 128, xa, scr2, tid);
        __syncthreads();
        if (tid < 256){
            float g = fsig(p.att_bg[h * 256 + tid] + red_parts<256,16>(scr, tid));
            g_l[h * 256 + tid] = g;
            cput(cm, CO_E2 + tid, g);
        }
        if (tid < 128){
            float cx = p.att_bc[h * 128 + tid] + red_parts<128,32>(scr2, tid);
            cx_l[h * 128 + tid] = cx;
            cput(cm, CO_E2 + 256 + tid, cx);
        }
        pair_wait(p.flags, fm, fo, ++seq, tid);
        if (tid < 256) g_l[(1 - h) * 256 + tid] = cget(co, CO_E2 + tid);
        if (tid < 128) cx_l[(1 - h) * 128 + tid] = cget(co, CO_E2 + 256 + tid);
        __syncthreads();

        // ---- P4: c-half = tanh(cx + (r*h)@Wc_h); own h_att slice update ----
        if (tid < 256) xbuf[tid] = g_l[tid] * xa[384 + tid];   // r*h (old h)
        __syncthreads();
        gemv_h<256, 256, 128, 32>(W + OFF_ATT_WCH + h * 128, xbuf, scr, tid);
        __syncthreads();
        if (tid < 128){
            int n = h * 128 + tid;
            float c = ftanh(cx_l[n] + red_parts<128,32>(scr, tid));
            float u = g_l[256 + n];
            xa[384 + n] = u * xa[384 + n] + (1.f - u) * c;    // own fresh slice
        }
        __syncthreads();

        // ---- P5: q partial over own fresh h_att slice (K-split) ----
        gemv_h<128, 256, 256, 16>(W + OFF_ATTN_WQ + (size_t)(h * 128) * 256,
                                  &xa[384 + h * 128], scr2, tid);
        __syncthreads();
        // ---- E3: h_att slice + q partial ----
        if (tid < 128) cput(cm, CO_E3 + tid, xa[384 + h * 128 + tid]);
        if (tid < 256) cput(cm, CO_E3 + 128 + tid, red_parts<256,16>(scr2, tid));
        pair_wait(p.flags, fm, fo, ++seq, tid);
        if (tid < 128) xa[384 + (1 - h) * 128 + tid] = cget(co, CO_E3 + tid);
        if (tid < 256)
            q_l[tid] = p.attn_bq[tid] + red_parts<256,16>(scr2, tid) + cget(co, CO_E3 + 128 + tid);
        __syncthreads();

        // ---- P6: energies over own t-half [h*512, h*512+512) ----
        {
            const int tc   = tid & 63;     // 64 chunks x 8 t
            const int part = tid >> 6;     // 8 parts x 32 d
            float a0=0.f,a1=0.f,a2=0.f,a3=0.f,a4=0.f,a5=0.f,a6=0.f,a7=0.f;
            if (h * 512 + tc * 8 < mlen){
                const unsigned short* kp = p.keysT + (((size_t)b) << 18)
                                         + ((size_t)(part * 32) << 10) + h * 512 + tc * 8;
                #pragma unroll 16
                for (int dd = 0; dd < 32; dd++){
                    uint4 kv = *(const uint4*)(kp + ((size_t)dd << 10));
                    int d = part * 32 + dd;
                    float qd = q_l[d], vd = v_l[d];
                    a0 = fmaf(ftanh(__uint_as_float(kv.x << 16)         + qd), vd, a0);
                    a1 = fmaf(ftanh(__uint_as_float(kv.x & 0xffff0000u) + qd), vd, a1);
                    a2 = fmaf(ftanh(__uint_as_float(kv.y << 16)         + qd), vd, a2);
                    a3 = fmaf(ftanh(__uint_as_float(kv.y & 0xffff0000u) + qd), vd, a3);
                    a4 = fmaf(ftanh(__uint_as_float(kv.z << 16)         + qd), vd, a4);
                    a5 = fmaf(ftanh(__uint_as_float(kv.z & 0xffff0000u) + qd), vd, a5);
                    a6 = fmaf(ftanh(__uint_as_float(kv.w << 16)         + qd), vd, a6);
                    a7 = fmaf(ftanh(__uint_as_float(kv.w & 0xffff0000u) + qd), vd, a7);
                }
            }
            float4* s4 = (float4*)(scr + part * 512 + tc * 8);
            s4[0] = float4{a0, a1, a2, a3};
            s4[1] = float4{a4, a5, a6, a7};
        }
        __syncthreads();
        float av;
        {
            float e = 0.f;
            #pragma unroll
            for (int pp = 0; pp < 8; pp++) e += scr[pp * 512 + tid];
            av = (h * 512 + tid < mlen) ? __expf(e) : 0.f;
            float ws = av;
            #pragma unroll
            for (int off = 32; off; off >>= 1) ws += __shfl_xor(ws, off, 64);
            if ((tid & 63) == 0) red[tid >> 6] = ws;
        }
        __syncthreads();
        if (tid == 0){
            float dl = 0.f;
            #pragma unroll
            for (int i = 0; i < 8; i++) dl += red[i];
            red[8] = dl;
            cput(cm, CO_E4, dl);
        }
        pair_wait(p.flags, fm, fo, ++seq, tid);
        {
            float total = red[8] + cget(co, CO_E4);
            float alpha = av * __builtin_amdgcn_rcpf(total);
            e_l[tid] = alpha;
            __builtin_nontemporal_store(alpha,
                &p.out[ALPHA_OFF + (size_t)s * 131072 + ((size_t)b << 10) + h * 512 + tid]);
        }
        __syncthreads();

        // ---- P7: context partial over own t-half ----
        {
            const int dc = tid & 31;       // 32 chunks x 8 d
            const int tp = tid >> 5;       // 16 t-parts
            float a0=0.f,a1=0.f,a2=0.f,a3=0.f,a4=0.f,a5=0.f,a6=0.f,a7=0.f;
            int mloc = mlen - h * 512;
            if (mloc > 512) mloc = 512;
            const unsigned short* er = p.encb + (((size_t)b) << 18)
                                     + ((size_t)(h * 512) << 8) + dc * 8;
            #pragma unroll 8
            for (int t = tp; t < mloc; t += 16){
                uint4 ev4 = *(const uint4*)(er + ((size_t)t << 8));
                float al = e_l[t];
                a0 = fmaf(al, __uint_as_float(ev4.x << 16),         a0);
                a1 = fmaf(al, __uint_as_float(ev4.x & 0xffff0000u), a1);
                a2 = fmaf(al, __uint_as_float(ev4.y << 16),         a2);
                a3 = fmaf(al, __uint_as_float(ev4.y & 0xffff0000u), a3);
                a4 = fmaf(al, __uint_as_float(ev4.z << 16),         a4);
                a5 = fmaf(al, __uint_as_float(ev4.z & 0xffff0000u), a5);
                a6 = fmaf(al, __uint_as_float(ev4.w << 16),         a6);
                a7 = fmaf(al, __uint_as_float(ev4.w & 0xffff0000u), a7);
            }
            float4* s4 = (float4*)(scr + tp * 256 + dc * 8);
            s4[0] = float4{a0, a1, a2, a3};
            s4[1] = float4{a4, a5, a6, a7};
        }
        __syncthreads();
        if (tid < 256) cput(cm, CO_E5 + tid, red_parts<256,16>(scr, tid));
        pair_wait(p.flags, fm, fo, ++seq, tid);
        if (tid < 256){
            float cs = red_parts<256,16>(scr, tid) + cget(co, CO_E5 + tid);
            xa[tid] = cs;                               // ctx for next step
            if (h == 0){
                float wpv = astylel[tid] * __builtin_amdgcn_rcpf(fabsf(cs) + astylel[tid]);
                #pragma unroll
                for (int off = 32; off; off >>= 1) wpv += __shfl_xor(wpv, off, 64);
                if ((tid & 63) == 0) atomicAdd(&p.wacc[s], wpv);
            }
        }
        __syncthreads();

        // ---- P8: dec_in = [h_att, wctx] @ deci_W, N-split ----
        xbuf[tid] = (tid < 256) ? xa[384 + tid] : xa[tid - 256] + stylel[tid - 256];
        __syncthreads();
        gemv_h<512, 256, 128, 32>(W + OFF_DECI_W + h * 128, xbuf, scr, tid);
        __syncthreads();
        if (tid < 128){
            float d = p.deci_b[h * 128 + tid] + red_parts<128,32>(scr, tid);
            dci[h * 128 + tid] = d;
            cput(cm, CO_E6 + tid, d);
        }
        pair_wait(p.flags, fm, fo, ++seq, tid);
        if (tid < 128) dci[(1 - h) * 128 + tid] = cget(co, CO_E6 + tid);
        __syncthreads();

        // ---- P9: dec1 A: g1, cx1 (N-split) ----
        xbuf[tid] = (tid < 256) ? dci[tid] : h1[tid - 256];
        __syncthreads();
        gemv_h<512, 512, 256, 16>(W + OFF_DEC1_WG + h * 256, xbuf, scr,  tid);
        gemv_h<256, 256, 128, 32>(W + OFF_DEC1_WC + h * 128, xbuf, scr2, tid);
        __syncthreads();
        if (tid < 256){
            float g = fsig(p.dec1_bg[h * 256 + tid] + red_parts<256,16>(scr, tid));
            g_l[h * 256 + tid] = g;
            cput(cm, CO_E7 + tid, g);
        }
        if (tid < 128){
            float cx = p.dec1_bc[h * 128 + tid] + red_parts<128,32>(scr2, tid);
            cx_l[h * 128 + tid] = cx;
            cput(cm, CO_E7 + 256 + tid, cx);
        }
        pair_wait(p.flags, fm, fo, ++seq, tid);
        if (tid < 256) g_l[(1 - h) * 256 + tid] = cget(co, CO_E7 + tid);
        if (tid < 128) cx_l[(1 - h) * 128 + tid] = cget(co, CO_E7 + 256 + tid);
        __syncthreads();

        // ---- P10: dec1 B (N-split) -> own h1/o1 slice ----
        if (tid < 256) xbuf[tid] = g_l[tid] * h1[tid];
        __syncthreads();
        gemv_h<256, 256, 128, 32>(W + OFF_DEC1_WCH + h * 128, xbuf, scr, tid);
        __syncthreads();
        if (tid < 128){
            int n = h * 128 + tid;
            float c = ftanh(cx_l[n] + red_parts<128,32>(scr, tid));
            float u = g_l[256 + n];
            float hn = u * h1[n] + (1.f - u) * c;
            h1[n] = hn;
            o1_l[n] = hn + dci[n];
        }
        __syncthreads();

        // ---- P11: dec2 A, K-split over {o1 slice, h2old half} (reordered Wg2)
        if (tid < 256)
            xbuf[tid] = (tid < 128) ? o1_l[h * 128 + tid] : h2[h * 128 + (tid - 128)];
        __syncthreads();
        gemv_h<256, 512, 512, 8>(W + OFF_DEC2_WG + (size_t)(h * 256) * 512, xbuf, scr, tid);
        gemv_h<128, 256, 256, 16>(W + OFF_DEC2_WC + (size_t)(h * 128) * 256, xbuf, scr2, tid);
        __syncthreads();
        // ---- E8: h1 slice + g2 partial + cx2 partial ----
        if (tid < 128) cput(cm, CO_E8 + tid, h1[h * 128 + tid]);
        cput(cm, CO_E8 + 128 + tid, red_parts<512,8>(scr, tid));
        if (tid < 256) cput(cm, CO_E8 + 640 + tid, red_parts<256,16>(scr2, tid));
        pair_wait(p.flags, fm, fo, ++seq, tid);
        g_l[tid] = fsig(p.dec2_bg[tid] + red_parts<512,8>(scr, tid) + cget(co, CO_E8 + 128 + tid));
        if (tid < 256)
            cx_l[tid] = p.dec2_bc[tid] + red_parts<256,16>(scr2, tid) + cget(co, CO_E8 + 640 + tid);
        if (tid < 128) h1[(1 - h) * 128 + tid] = cget(co, CO_E8 + tid);
        __syncthreads();

        // ---- P12: dec2 B (N-split) -> own h2/o2 slice ----
        if (tid < 256) xbuf[tid] = g_l[tid] * h2[tid];
        __syncthreads();
        gemv_h<256, 256, 128, 32>(W + OFF_DEC2_WCH + h * 128, xbuf, scr, tid);
        __syncthreads();
        if (tid < 128){
            int n = h * 128 + tid;
            float c = ftanh(cx_l[n] + red_parts<128,32>(scr, tid));
            float u = g_l[256 + n];
            float hn = u * h2[n] + (1.f - u) * c;
            h2[n] = hn;
            o2loc[tid] = hn + o1_l[n];
        }
        __syncthreads();

        // ---- P13: output dense, K-split over own o2 slice ----
        gemv_h<128, 512, 512, 8>(W + OFF_OUT_WP + (size_t)(h * 128) * 512, o2loc, scr2, tid);
        __syncthreads();
        // ---- E9: h2 slice + dense partial ----
        if (tid < 128) cput(cm, CO_E9 + tid, h2[h * 128 + tid]);
        cput(cm, CO_E9 + 128 + tid, red_parts<512,8>(scr2, tid));
        pair_wait(p.flags, fm, fo, ++seq, tid);
        {
            float bias = (tid < 400) ? p.out_b[tid] : 0.f;
            float dv = bias + red_parts<512,8>(scr2, tid) + cget(co, CO_E9 + 128 + tid);
            if (tid >= 320 && tid < 400) last_o[tid - 320] = dv;
            bool mine = h ? (tid >= 256 && tid < 400) : (tid < 256);
            if (mine)
                __builtin_nontemporal_store(dv,
                    &p.out[(size_t)b * 100000 + (size_t)s * 400 + tid]);
        }
        if (tid < 128) h2[(1 - h) * 128 + tid] = cget(co, CO_E9 + tid);
        __syncthreads();
    }
}

// ---------------- K3: finalize weight_pers ----------------------------------
__global__ void k_final(const float* __restrict__ wacc, float* __restrict__ out)
{
    int i = threadIdx.x;
    if (i < TDEC) out[WP_OFF + i] = wacc[i] * (1.0f / 32768.0f);
}

// ---------------------------------------------------------------------------
extern "C" void kernel_launch(void* const* d_in, const int* in_sizes, int n_in,
                              void* d_out, int out_size, void* d_ws, size_t ws_size,
                              hipStream_t stream)
{
    const float* enc        = (const float*)d_in[0];
    const int*   imask      = (const int*)  d_in[1];
    const float* inp_att    = (const float*)d_in[2];
    const float* style_tok  = (const float*)d_in[3];
    const float* pre_W1     = (const float*)d_in[4];
    const float* pre_b1     = (const float*)d_in[5];
    const float* pre_W2     = (const float*)d_in[6];
    const float* pre_b2     = (const float*)d_in[7];
    const float* att_Wg     = (const float*)d_in[8];
    const float* att_bg     = (const float*)d_in[9];
    const float* att_Wc     = (const float*)d_in[10];
    const float* att_bc     = (const float*)d_in[11];
    const float* attn_Wk    = (const float*)d_in[12];
    const float* attn_bk    = (const float*)d_in[13];
    const float* attn_Wq    = (const float*)d_in[14];
    const float* attn_bq    = (const float*)d_in[15];
    const float* attn_v     = (const float*)d_in[16];
    const float* deci_W     = (const float*)d_in[17];
    const float* deci_b     = (const float*)d_in[18];
    const float* dec1_Wg    = (const float*)d_in[19];
    const float* dec1_bg    = (const float*)d_in[20];
    const float* dec1_Wc    = (const float*)d_in[21];
    const float* dec1_bc    = (const float*)d_in[22];
    const float* dec2_Wg    = (const float*)d_in[23];
    const float* dec2_bg    = (const float*)d_in[24];
    const float* dec2_Wc    = (const float*)d_in[25];
    const float* dec2_bc    = (const float*)d_in[26];
    const float* out_W      = (const float*)d_in[27];
    const float* out_b      = (const float*)d_in[28];

    float*          wacc  = (float*)((char*)d_ws + WS_WACC_B);
    int*            flags = (int*)  ((char*)d_ws + WS_FLAG_B);
    float*          comm  = (float*)((char*)d_ws + WS_COMM_B);
    unsigned short* wgt   = (unsigned short*)((char*)d_ws + WS_WGT_B);
    unsigned short* keysT = (unsigned short*)((char*)d_ws + WS_KEYS_B);
    unsigned short* encb  = (unsigned short*)((char*)d_ws + WS_ENC_B);
    float* out = (float*)d_out;

    hipMemsetAsync(d_ws, 0, 2048, stream);   // wacc + flags

    auto cvt = [&](const float* src, size_t off, int n){
        k_cvt_flat<<<(n + 255) / 256, 256, 0, stream>>>(src, wgt + off, n);
    };
    cvt(pre_W1,  OFF_PRE_W1,   80 * 256);
    cvt(pre_W2,  OFF_PRE_W2,  256 * 128);
    cvt(att_Wg,  OFF_ATT_WG,  640 * 512);
    cvt(att_Wc,  OFF_ATT_WC,  640 * 256);
    cvt(attn_Wq, OFF_ATTN_WQ, 256 * 256);
    cvt(deci_W,  OFF_DECI_W,  512 * 256);
    cvt(dec1_Wg, OFF_DEC1_WG, 512 * 512);
    cvt(dec1_Wc, OFF_DEC1_WC, 512 * 256);
    k_cvt_wg2<<<(512 * 512) / 256, 256, 0, stream>>>(dec2_Wg, wgt + OFF_DEC2_WG);
    cvt(dec2_Wc, OFF_DEC2_WC, 512 * 256);
    k_cvt_pad<<<(256 * 512) / 256, 256, 0, stream>>>(out_W, wgt + OFF_OUT_WP);

    k_cvt_flat<<<(33554432 + 255) / 256, 256, 0, stream>>>(enc, encb, 33554432);
    k_keys<<<2048, 256, 0, stream>>>(enc, attn_Wk, attn_bk, keysT);

    KParams kp{imask, inp_att, style_tok,
               pre_b1, pre_b2, att_bg, att_bc, attn_bq, attn_v,
               deci_b, dec1_bg, dec1_bc, dec2_bg, dec2_bc, out_b,
               wgt, keysT, encb, wacc, comm, flags, out};
    k_main<<<2 * BATCH, 512, 0, stream>>>(kp);

    k_final<<<1, 256, 0, stream>>>(wacc, out);
}

// Round 4
// 24379.890 us; speedup vs baseline: 1.1107x; 1.1107x over previous
//
#include <hip/hip_runtime.h>
#include <cstdint>
#include <cstddef>

// ---------------------------------------------------------------------------
// Tacotron decoder, MI355X. Round 6: R1 structure + non-temporal streaming.
// (R5 resubmit — fixed: __builtin_nontemporal_load needs a NATIVE vector
// type, not HIP's uint4 class. Using ext_vector_type(4) alias.)
// Theory: weights (3.3MB/step/block, same bytes every step) chronically
// MISS the 4MB per-XCD L2 because 16 blocks/XCD also stream ~12MB/step of
// distinct keysT/encb rows through it. Weight reads fall to Infinity Cache
// (~700cy, chip-shared BW) -> the ~50us/step unexplained stall.
// Fix: keysT (energy) and encb (context) loads non-temporal (evict-first,
// no L2 pollution) so the weight set stays L2-resident.
// ---------------------------------------------------------------------------

#define TDEC   250
#define BATCH  128

#define ALPHA_OFF  ((size_t)12800000)        // 128*1250*80 floats
#define WP_OFF     ((size_t)45568000)

// ---- ws byte offsets ----
#define WS_WACC_B   ((size_t)0)
#define WS_WGT_B    ((size_t)4096)
#define WGT_ELEMS   1658880
#define WS_KEYS_B   (WS_WGT_B + (size_t)WGT_ELEMS * 2)
#define WS_ENC_B    (WS_KEYS_B + (size_t)33554432 * 2)

// ---- weight offsets (bf16 elems) ----
#define OFF_PRE_W1   0          // 80x256
#define OFF_PRE_W2   20480      // 256x128
#define OFF_ATT_WG   53248      // 640x512
#define OFF_ATT_WC   380928     // 640x256 (rows 0..383 = x-part)
#define OFF_ATT_WCH  479232     // rows 384..639 (r*h part)
#define OFF_ATTN_WQ  544768     // 256x256
#define OFF_DECI_W   610304     // 512x256
#define OFF_DEC1_WG  741376     // 512x512
#define OFF_DEC1_WC  1003520    // 512x256 (rows 0..255 = x-part)
#define OFF_DEC1_WCH 1069056    // rows 256..511
#define OFF_DEC2_WG  1134592    // 512x512
#define OFF_DEC2_WC  1396736    // 512x256
#define OFF_DEC2_WCH 1462272    // rows 256..511
#define OFF_OUT_WP   1527808    // 256x512 (padded from 256x400)

typedef unsigned int u32x4 __attribute__((ext_vector_type(4)));

__device__ inline unsigned short f2bf(float f){
    unsigned int u = __float_as_uint(f);
    u = (u + 0x7fffu + ((u >> 16) & 1u)) >> 16;
    return (unsigned short)u;
}
__device__ inline float ftanh(float x){
    float e = __expf(2.f * x);
    return 1.f - 2.f * __builtin_amdgcn_rcpf(e + 1.f);
}
__device__ inline float fsig(float x){
    return __builtin_amdgcn_rcpf(1.f + __expf(-x));
}

// ---------------- bf16 GEMV partials: scratch[part][N] = x_part @ W_part ----
template<int K, int N, int PARTS>
__device__ inline void gemv_part(const unsigned short* __restrict__ W,
                                 const float* __restrict__ x,
                                 float* __restrict__ scratch, int tid)
{
    constexpr int CH   = N / 8;
    constexpr int LG   = (CH == 16) ? 4 : (CH == 32) ? 5 : 6;
    constexpr int KCNT = K / PARTS;
    static_assert(KCNT * PARTS == K, "K must divide");
    static_assert(CH * PARTS <= 1024, "too many threads");
    const int chunk = tid & (CH - 1);
    const int part  = tid >> LG;
    if (PARTS == (1024 >> LG) || part < PARTS){
        const uint4* Wp = (const uint4*)W + (size_t)(part * KCNT) * (N / 8) + chunk;
        const float* xp = x + part * KCNT;
        float a0=0.f,a1=0.f,a2=0.f,a3=0.f,a4=0.f,a5=0.f,a6=0.f,a7=0.f;
        #pragma unroll 8
        for (int k = 0; k < KCNT; k++){
            uint4 w = Wp[(size_t)k * (N / 8)];
            float xv = xp[k];
            a0 = fmaf(__uint_as_float(w.x << 16),         xv, a0);
            a1 = fmaf(__uint_as_float(w.x & 0xffff0000u), xv, a1);
            a2 = fmaf(__uint_as_float(w.y << 16),         xv, a2);
            a3 = fmaf(__uint_as_float(w.y & 0xffff0000u), xv, a3);
            a4 = fmaf(__uint_as_float(w.z << 16),         xv, a4);
            a5 = fmaf(__uint_as_float(w.z & 0xffff0000u), xv, a5);
            a6 = fmaf(__uint_as_float(w.w << 16),         xv, a6);
            a7 = fmaf(__uint_as_float(w.w & 0xffff0000u), xv, a7);
        }
        float4* s4 = (float4*)(scratch + part * N + chunk * 8);
        s4[0] = float4{a0, a1, a2, a3};
        s4[1] = float4{a4, a5, a6, a7};
    }
}

template<int N, int PARTS>
__device__ inline float red_parts(const float* __restrict__ scratch, int n){
    float s = 0.f;
    #pragma unroll
    for (int p = 0; p < PARTS; p++) s += scratch[p * N + n];
    return s;
}

// ---------------- prep: fp32 -> bf16 conversions ----------------------------
__global__ void k_cvt_flat(const float* __restrict__ src, unsigned short* __restrict__ dst, int n){
    int i = blockIdx.x * 256 + threadIdx.x;
    if (i < n) dst[i] = f2bf(src[i]);
}
__global__ void k_cvt_pad(const float* __restrict__ src, unsigned short* __restrict__ dst){
    int i = blockIdx.x * 256 + threadIdx.x;   // i < 256*512
    int k = i >> 9, n = i & 511;
    dst[i] = (n < 400) ? f2bf(src[k * 400 + n]) : (unsigned short)0;
}

// ---------------- K1: keys_T[b][d][t] = bf16(enc @ Wk + bk) -----------------
__global__ __launch_bounds__(256) void k_keys(const float* __restrict__ enc,
                                              const float* __restrict__ Wk,
                                              const float* __restrict__ bk,
                                              unsigned short* __restrict__ keysT)
{
    __shared__ __align__(16) float Wt[64 * 256];   // [kk][d]
    __shared__ float At[64 * 64];                  // [r][kk]
    __shared__ unsigned short tileT[256 * 68];     // [d][t_loc], pad 68
    const int tid = threadIdx.x;
    const size_t row0 = (size_t)blockIdx.x * 64;
    const int dq = tid & 63;
    const int rg = tid >> 6;

    float4 acc[16];
    #pragma unroll
    for (int i = 0; i < 16; i++) acc[i] = float4{0.f, 0.f, 0.f, 0.f};

    for (int k0 = 0; k0 < 256; k0 += 64){
        __syncthreads();
        #pragma unroll
        for (int i = 0; i < 64; i++)
            Wt[i * 256 + tid] = Wk[(size_t)(k0 + i) * 256 + tid];
        #pragma unroll
        for (int i = 0; i < 16; i++){
            int idx = tid + i * 256;
            int r = idx >> 6, kk = idx & 63;
            At[idx] = enc[(row0 + r) * 256 + k0 + kk];
        }
        __syncthreads();
        for (int kk = 0; kk < 64; kk++){
            float4 w = ((const float4*)Wt)[kk * 64 + dq];
            #pragma unroll
            for (int rr = 0; rr < 16; rr++){
                float a = At[(rg * 16 + rr) * 64 + kk];
                acc[rr].x += a * w.x; acc[rr].y += a * w.y;
                acc[rr].z += a * w.z; acc[rr].w += a * w.w;
            }
        }
    }
    float4 bb = ((const float4*)bk)[dq];
    __syncthreads();
    #pragma unroll
    for (int rr = 0; rr < 16; rr++){
        int t_loc = rg * 16 + rr;
        #pragma unroll
        for (int c = 0; c < 4; c++){
            float val = (&acc[rr].x)[c] + (&bb.x)[c];
            int d = dq * 4 + c;
            tileT[d * 68 + t_loc] = f2bf(val);
        }
    }
    __syncthreads();
    const int b_ = (int)(row0 >> 10);
    const int t0 = (int)(row0 & 1023);
    #pragma unroll
    for (int i = 0; i < 16; i++){
        int flat = tid + i * 256;
        int d = flat >> 4, tq = flat & 15;
        ushort4 v = *(const ushort4*)&tileT[d * 68 + tq * 4];
        *(ushort4*)&keysT[(((size_t)(b_ * 256 + d)) << 10) + t0 + tq * 4] = v;
    }
}

// ---------------- K2: main recurrent kernel, block = batch row b ------------
struct KParams {
    const int *imask; const float *inp_att; const float *style_tok;
    const float *pre_b1, *pre_b2, *att_bg, *att_bc, *attn_bq, *attn_v;
    const float *deci_b, *dec1_bg, *dec1_bc, *dec2_bg, *dec2_bc, *out_b;
    const unsigned short *wgt;      // bf16 weight block
    const unsigned short *keysT;    // [128][256][1024] bf16
    const unsigned short *encb;     // [128][1024][256] bf16
    float *wacc; float *out;
};

__global__ __launch_bounds__(1024, 1) void k_main(KParams p)
{
    __shared__ __align__(16) float scr [8192];     // GEMV/attention partials
    __shared__ __align__(16) float scr2[8192];     // second partial buffer
    __shared__ float xa[640];                       // [ctx, p, h_att] (att GRU in)
    __shared__ float xg[512];                       // [x, h] (dec GRU in)
    __shared__ float xr[256];                       // r*h
    __shared__ float xd[512];                       // [h_att, wctx]
    __shared__ float g_l[512], cx_l[256];
    __shared__ float h_att[256], h1[256], h2[256];
    __shared__ float p1_l[256], dci[256], o1_l[256], o2_l[256];
    __shared__ float stylel[256], astylel[256], v_l[256], q_l[256];
    __shared__ float e_l[1024];
    __shared__ float last_o[80];
    __shared__ float red[16];

    const int tid = threadIdx.x;
    const int b   = blockIdx.x;
    const int mlen = p.imask[b];          // 1..1024
    const unsigned short* W = p.wgt;

    if (tid < 256){
        h_att[tid] = 0.f; h1[tid] = 0.f; h2[tid] = 0.f;
        float s = 0.f;
        #pragma unroll
        for (int k = 0; k < 10; k++) s += p.inp_att[b * 10 + k] * p.style_tok[k * 256 + tid];
        stylel[tid] = s; astylel[tid] = fabsf(s);
        v_l[tid] = p.attn_v[tid];
        xa[tid] = 0.f;            // ctx = 0
        xa[384 + tid] = 0.f;      // h_att = 0
    }
    if (tid < 80) last_o[tid] = 0.f;
    __syncthreads();

    for (int s = 0; s < TDEC; s++){
        // ---- P1: prenet1 (80 -> 256, relu) ----
        gemv_part<80, 256, 16>(W + OFF_PRE_W1, last_o, scr, tid);
        __syncthreads();
        if (tid < 256)
            p1_l[tid] = fmaxf(p.pre_b1[tid] + red_parts<256,16>(scr, tid), 0.f);
        __syncthreads();

        // ---- P2: prenet2 (256 -> 128, relu) -> xa[256..383] ----
        gemv_part<256, 128, 64>(W + OFF_PRE_W2, p1_l, scr, tid);
        __syncthreads();
        if (tid < 128)
            xa[256 + tid] = fmaxf(p.pre_b2[tid] + red_parts<128,64>(scr, tid), 0.f);
        __syncthreads();

        // ---- P3: att GRU phase A: g = sig(xa@Wg), cx = bc + xa[0:384]@Wc_x
        gemv_part<640, 512, 16>(W + OFF_ATT_WG, xa, scr,  tid);
        gemv_part<384, 256, 32>(W + OFF_ATT_WC, xa, scr2, tid);
        __syncthreads();
        if (tid < 512){
            float g = fsig(p.att_bg[tid] + red_parts<512,16>(scr, tid));
            g_l[tid] = g;
            if (tid < 256) xr[tid] = g * h_att[tid];        // r*h
        } else if (tid < 768){
            int n = tid - 512;
            cx_l[n] = p.att_bc[n] + red_parts<256,32>(scr2, n);
        }
        __syncthreads();

        // ---- P4: att GRU phase B: c = tanh(cx + (r*h)@Wc_h); h update ----
        gemv_part<256, 256, 32>(W + OFF_ATT_WCH, xr, scr, tid);
        __syncthreads();
        if (tid < 256){
            float c = ftanh(cx_l[tid] + red_parts<256,32>(scr, tid));
            float u = g_l[256 + tid];
            float h = u * h_att[tid] + (1.f - u) * c;
            h_att[tid] = h;
            xa[384 + tid] = h;     // for next step's P3
            xd[tid] = h;           // for P8 (deci)
        }
        __syncthreads();

        // ---- P5: q = h_att @ Wq + bq ----
        gemv_part<256, 256, 32>(W + OFF_ATTN_WQ, h_att, scr, tid);
        __syncthreads();
        if (tid < 256) q_l[tid] = p.attn_bq[tid] + red_parts<256,32>(scr, tid);
        __syncthreads();

        // ---- P6: energy e[t] = sum_d tanh(keysT[d][t]+q[d])*v[d]; softmax
        // (max-free: |e| <= sum|v| ~ 10, exp safe in fp32)
        // keysT loads NON-TEMPORAL: don't evict L2-resident weights.
        {
            const int tc   = tid & 127;
            const int part = tid >> 7;
            float acc0=0.f,acc1=0.f,acc2=0.f,acc3=0.f,acc4=0.f,acc5=0.f,acc6=0.f,acc7=0.f;
            if (tc * 8 < mlen){
                const unsigned short* kp = p.keysT + (((size_t)b) << 18)
                                         + ((size_t)(part * 32) << 10) + tc * 8;
                #pragma unroll 16
                for (int dd = 0; dd < 32; dd++){
                    u32x4 kv = __builtin_nontemporal_load((const u32x4*)(kp + ((size_t)dd << 10)));
                    int d = part * 32 + dd;
                    float qd = q_l[d], vd = v_l[d];
                    acc0 = fmaf(ftanh(__uint_as_float(kv.x << 16)         + qd), vd, acc0);
                    acc1 = fmaf(ftanh(__uint_as_float(kv.x & 0xffff0000u) + qd), vd, acc1);
                    acc2 = fmaf(ftanh(__uint_as_float(kv.y << 16)         + qd), vd, acc2);
                    acc3 = fmaf(ftanh(__uint_as_float(kv.y & 0xffff0000u) + qd), vd, acc3);
                    acc4 = fmaf(ftanh(__uint_as_float(kv.z << 16)         + qd), vd, acc4);
                    acc5 = fmaf(ftanh(__uint_as_float(kv.z & 0xffff0000u) + qd), vd, acc5);
                    acc6 = fmaf(ftanh(__uint_as_float(kv.w << 16)         + qd), vd, acc6);
                    acc7 = fmaf(ftanh(__uint_as_float(kv.w & 0xffff0000u) + qd), vd, acc7);
                }
            }
            float4* s4 = (float4*)(scr + part * 1024 + tc * 8);
            s4[0] = float4{acc0, acc1, acc2, acc3};
            s4[1] = float4{acc4, acc5, acc6, acc7};
        }
        __syncthreads();
        float av = 0.f;
        if (tid < mlen){
            float s8 = 0.f;
            #pragma unroll
            for (int pp = 0; pp < 8; pp++) s8 += scr[pp * 1024 + tid];
            av = __expf(s8);
        }
        {   // block sum: per-wave shuffle -> 16 LDS -> broadcast sum
            float ws = av;
            #pragma unroll
            for (int off = 32; off; off >>= 1) ws += __shfl_xor(ws, off, 64);
            if ((tid & 63) == 0) red[tid >> 6] = ws;
        }
        __syncthreads();
        {
            float tot = 0.f;
            #pragma unroll
            for (int i = 0; i < 16; i++) tot += red[i];
            float alpha = av * __builtin_amdgcn_rcpf(tot);
            e_l[tid] = alpha;
            __builtin_nontemporal_store(alpha,
                &p.out[ALPHA_OFF + (size_t)s * 131072 + ((size_t)b << 10) + tid]);
        }
        __syncthreads();

        // ---- P7: context ctx[d] = sum_t alpha[t]*enc[t][d]; fills xa/xd, wp
        // encb loads NON-TEMPORAL: don't evict L2-resident weights.
        {
            const int dc = tid & 31;
            const int tp = tid >> 5;
            float acc0=0.f,acc1=0.f,acc2=0.f,acc3=0.f,acc4=0.f,acc5=0.f,acc6=0.f,acc7=0.f;
            const unsigned short* er = p.encb + (((size_t)b) << 18) + dc * 8;
            #pragma unroll 8
            for (int t = tp; t < mlen; t += 32){
                u32x4 ev4 = __builtin_nontemporal_load((const u32x4*)(er + ((size_t)t << 8)));
                float al = e_l[t];
                acc0 = fmaf(al, __uint_as_float(ev4.x << 16),         acc0);
                acc1 = fmaf(al, __uint_as_float(ev4.x & 0xffff0000u), acc1);
                acc2 = fmaf(al, __uint_as_float(ev4.y << 16),         acc2);
                acc3 = fmaf(al, __uint_as_float(ev4.y & 0xffff0000u), acc3);
                acc4 = fmaf(al, __uint_as_float(ev4.z << 16),         acc4);
                acc5 = fmaf(al, __uint_as_float(ev4.z & 0xffff0000u), acc5);
                acc6 = fmaf(al, __uint_as_float(ev4.w << 16),         acc6);
                acc7 = fmaf(al, __uint_as_float(ev4.w & 0xffff0000u), acc7);
            }
            float4* s4 = (float4*)(scr + tp * 256 + dc * 8);
            s4[0] = float4{acc0, acc1, acc2, acc3};
            s4[1] = float4{acc4, acc5, acc6, acc7};
        }
        __syncthreads();
        if (tid < 256){
            float cs = red_parts<256,32>(scr, tid);
            xa[tid] = cs;                        // ctx for next step's P3
            xd[256 + tid] = cs + stylel[tid];    // wctx for P8
            float wpv = astylel[tid] * __builtin_amdgcn_rcpf(fabsf(cs) + astylel[tid]);
            #pragma unroll
            for (int off = 32; off; off >>= 1) wpv += __shfl_xor(wpv, off, 64);
            if ((tid & 63) == 0) atomicAdd(&p.wacc[s], wpv);
        }
        __syncthreads();

        // ---- P8: dec_in = [h_att, wctx] @ deci_W + b ----
        gemv_part<512, 256, 32>(W + OFF_DECI_W, xd, scr, tid);
        __syncthreads();
        if (tid < 256){
            float d = p.deci_b[tid] + red_parts<256,32>(scr, tid);
            dci[tid] = d;
            xg[tid] = d; xg[256 + tid] = h1[tid];
        }
        __syncthreads();

        // ---- P9: dec1 phase A ----
        gemv_part<512, 512, 16>(W + OFF_DEC1_WG, xg, scr,  tid);
        gemv_part<256, 256, 32>(W + OFF_DEC1_WC, xg, scr2, tid);   // x-part only
        __syncthreads();
        if (tid < 512){
            float g = fsig(p.dec1_bg[tid] + red_parts<512,16>(scr, tid));
            g_l[tid] = g;
            if (tid < 256) xr[tid] = g * h1[tid];
        } else if (tid < 768){
            int n = tid - 512;
            cx_l[n] = p.dec1_bc[n] + red_parts<256,32>(scr2, n);
        }
        __syncthreads();

        // ---- P10: dec1 phase B ----
        gemv_part<256, 256, 32>(W + OFF_DEC1_WCH, xr, scr, tid);
        __syncthreads();
        if (tid < 256){
            float c = ftanh(cx_l[tid] + red_parts<256,32>(scr, tid));
            float u = g_l[256 + tid];
            float hn = u * h1[tid] + (1.f - u) * c;
            h1[tid] = hn;
            float o1 = hn + dci[tid];
            o1_l[tid] = o1;
            xg[tid] = o1; xg[256 + tid] = h2[tid];
        }
        __syncthreads();

        // ---- P11: dec2 phase A ----
        gemv_part<512, 512, 16>(W + OFF_DEC2_WG, xg, scr,  tid);
        gemv_part<256, 256, 32>(W + OFF_DEC2_WC, xg, scr2, tid);
        __syncthreads();
        if (tid < 512){
            float g = fsig(p.dec2_bg[tid] + red_parts<512,16>(scr, tid));
            g_l[tid] = g;
            if (tid < 256) xr[tid] = g * h2[tid];
        } else if (tid < 768){
            int n = tid - 512;
            cx_l[n] = p.dec2_bc[n] + red_parts<256,32>(scr2, n);
        }
        __syncthreads();

        // ---- P12: dec2 phase B ----
        gemv_part<256, 256, 32>(W + OFF_DEC2_WCH, xr, scr, tid);
        __syncthreads();
        if (tid < 256){
            float c = ftanh(cx_l[tid] + red_parts<256,32>(scr, tid));
            float u = g_l[256 + tid];
            float hn = u * h2[tid] + (1.f - u) * c;
            h2[tid] = hn;
            o2_l[tid] = hn + o1_l[tid];
        }
        __syncthreads();

        // ---- P13: output dense (256 -> 400 via padded 512) ----
        gemv_part<256, 512, 16>(W + OFF_OUT_WP, o2_l, scr, tid);
        __syncthreads();
        if (tid < 400){
            float val = p.out_b[tid] + red_parts<512,16>(scr, tid);
            __builtin_nontemporal_store(val,
                &p.out[(size_t)b * 100000 + (size_t)s * 400 + tid]);
            if (tid >= 320) last_o[tid - 320] = val;
        }
        __syncthreads();
    }
}

// ---------------- K3: finalize weight_pers ----------------------------------
__global__ void k_final(const float* __restrict__ wacc, float* __restrict__ out)
{
    int i = threadIdx.x;
    if (i < TDEC) out[WP_OFF + i] = wacc[i] * (1.0f / 32768.0f);
}

// ---------------------------------------------------------------------------
extern "C" void kernel_launch(void* const* d_in, const int* in_sizes, int n_in,
                              void* d_out, int out_size, void* d_ws, size_t ws_size,
                              hipStream_t stream)
{
    const float* enc        = (const float*)d_in[0];
    const int*   imask      = (const int*)  d_in[1];
    const float* inp_att    = (const float*)d_in[2];
    const float* style_tok  = (const float*)d_in[3];
    const float* pre_W1     = (const float*)d_in[4];
    const float* pre_b1     = (const float*)d_in[5];
    const float* pre_W2     = (const float*)d_in[6];
    const float* pre_b2     = (const float*)d_in[7];
    const float* att_Wg     = (const float*)d_in[8];
    const float* att_bg     = (const float*)d_in[9];
    const float* att_Wc     = (const float*)d_in[10];
    const float* att_bc     = (const float*)d_in[11];
    const float* attn_Wk    = (const float*)d_in[12];
    const float* attn_bk    = (const float*)d_in[13];
    const float* attn_Wq    = (const float*)d_in[14];
    const float* attn_bq    = (const float*)d_in[15];
    const float* attn_v     = (const float*)d_in[16];
    const float* deci_W     = (const float*)d_in[17];
    const float* deci_b     = (const float*)d_in[18];
    const float* dec1_Wg    = (const float*)d_in[19];
    const float* dec1_bg    = (const float*)d_in[20];
    const float* dec1_Wc    = (const float*)d_in[21];
    const float* dec1_bc    = (const float*)d_in[22];
    const float* dec2_Wg    = (const float*)d_in[23];
    const float* dec2_bg    = (const float*)d_in[24];
    const float* dec2_Wc    = (const float*)d_in[25];
    const float* dec2_bc    = (const float*)d_in[26];
    const float* out_W      = (const float*)d_in[27];
    const float* out_b      = (const float*)d_in[28];

    float*          wacc  = (float*)((char*)d_ws + WS_WACC_B);
    unsigned short* wgt   = (unsigned short*)((char*)d_ws + WS_WGT_B);
    unsigned short* keysT = (unsigned short*)((char*)d_ws + WS_KEYS_B);
    unsigned short* encb  = (unsigned short*)((char*)d_ws + WS_ENC_B);
    float* out = (float*)d_out;

    hipMemsetAsync(d_ws, 0, 1024, stream);

    // ---- weight conversions (bf16) ----
    auto cvt = [&](const float* src, size_t off, int n){
        k_cvt_flat<<<(n + 255) / 256, 256, 0, stream>>>(src, wgt + off, n);
    };
    cvt(pre_W1,  OFF_PRE_W1,   80 * 256);
    cvt(pre_W2,  OFF_PRE_W2,  256 * 128);
    cvt(att_Wg,  OFF_ATT_WG,  640 * 512);
    cvt(att_Wc,  OFF_ATT_WC,  640 * 256);
    cvt(attn_Wq, OFF_ATTN_WQ, 256 * 256);
    cvt(deci_W,  OFF_DECI_W,  512 * 256);
    cvt(dec1_Wg, OFF_DEC1_WG, 512 * 512);
    cvt(dec1_Wc, OFF_DEC1_WC, 512 * 256);
    cvt(dec2_Wg, OFF_DEC2_WG, 512 * 512);
    cvt(dec2_Wc, OFF_DEC2_WC, 512 * 256);
    k_cvt_pad<<<(256 * 512) / 256, 256, 0, stream>>>(out_W, wgt + OFF_OUT_WP);

    // ---- enc -> bf16 ----
    k_cvt_flat<<<(33554432 + 255) / 256, 256, 0, stream>>>(enc, encb, 33554432);

    // ---- keys (transposed bf16) ----
    k_keys<<<2048, 256, 0, stream>>>(enc, attn_Wk, attn_bk, keysT);

    KParams kp{imask, inp_att, style_tok,
               pre_b1, pre_b2, att_bg, att_bc, attn_bq, attn_v,
               deci_b, dec1_bg, dec1_bc, dec2_bg, dec2_bc, out_b,
               wgt, keysT, encb, wacc, out};
    k_main<<<BATCH, 1024, 0, stream>>>(kp);

    k_final<<<1, 256, 0, stream>>>(wacc, out);
}